// Round 5
// baseline (1699.058 us; speedup 1.0000x reference)
//
#include <hip/hip_runtime.h>
#include <hip/hip_bf16.h>

// Problem dims (fixed by the reference)
#define M_TOTAL 8192     // B*T = 4*2048
#define K_DIM   4096     // n (input dim, normalized over)
#define H_DIM   16384    // n_hidden

#define BM 256
#define BN 256
#define BK 64
#define NKT (K_DIM / BK)   // 64 K-tiles

typedef __attribute__((ext_vector_type(8)))  short  short8;   // 8 bf16 = 4 VGPRs
typedef __attribute__((ext_vector_type(4)))  float  f32x4;
typedef __attribute__((ext_vector_type(16))) float  f32x16;   // 32x32 acc
typedef __attribute__((ext_vector_type(8)))  unsigned short u16x8;

// RNE float -> bf16
static __device__ __forceinline__ unsigned short f2bf(float f) {
    unsigned int x = __float_as_uint(f);
    x += 0x7fffu + ((x >> 16) & 1u);
    return (unsigned short)(x >> 16);
}

// ---------------------------------------------------------------------------
// Kernel 1: straight cast g (fp32, [M][K]) -> bf16
// ---------------------------------------------------------------------------
__global__ void cast_bf16_kernel(const float* __restrict__ in,
                                 unsigned short* __restrict__ out, long n) {
    long i = ((long)blockIdx.x * blockDim.x + threadIdx.x) * 8;
    if (i >= n) return;
    const float4* p = (const float4*)(in + i);
    float4 a = p[0];
    float4 b = p[1];
    u16x8 o;
    o[0] = f2bf(a.x); o[1] = f2bf(a.y); o[2] = f2bf(a.z); o[3] = f2bf(a.w);
    o[4] = f2bf(b.x); o[5] = f2bf(b.y); o[6] = f2bf(b.z); o[7] = f2bf(b.w);
    *(u16x8*)(out + i) = o;
}

// ---------------------------------------------------------------------------
// Kernel 2: W [K][H] fp32 -> Wt [H][K] bf16  (LDS 64x64 tile transpose)
//           + fused column sum-of-squares into norm2[H]
// ---------------------------------------------------------------------------
__global__ void transpose_norm_kernel(const float* __restrict__ W,
                                      unsigned short* __restrict__ Wt,
                                      float* __restrict__ norm2) {
    __shared__ float tile[64][65];   // +1 pad
    __shared__ float np[64];
    const int h0 = blockIdx.x * 64;
    const int n0 = blockIdx.y * 64;
    const int t  = threadIdx.x;
    const int c  = t & 63;           // fast dim (coalesced global read over h)
    const int r4 = t >> 6;           // 0..3

    if (t < 64) np[t] = 0.f;
    __syncthreads();

    float sq = 0.f;
#pragma unroll
    for (int it = 0; it < 16; ++it) {
        int r = it * 4 + r4;         // n-row within tile
        float v = W[(size_t)(n0 + r) * H_DIM + h0 + c];
        tile[r][c] = v;              // tile[n][h]
        sq += v * v;
    }
    atomicAdd(&np[c], sq);           // LDS atomic, per h-column
    __syncthreads();

    // Write: Wt[h][n], each lane emits 16B (8 bf16 along n)
    const int chunk = t & 7;         // n-chunk (8 elements)
    const int hr    = t >> 3;        // 0..31
#pragma unroll
    for (int it = 0; it < 2; ++it) {
        int hrow = hr + it * 32;
        u16x8 o;
#pragma unroll
        for (int j = 0; j < 8; ++j)
            o[j] = f2bf(tile[chunk * 8 + j][hrow]);
        *(u16x8*)&Wt[(size_t)(h0 + hrow) * K_DIM + n0 + chunk * 8] = o;
    }
    if (t < 64) atomicAdd(&norm2[h0 + t], np[t]);
}

// ---------------------------------------------------------------------------
// Kernel 3: 256x256 / BK=64 / 8-wave GEMM using v_mfma_f32_32x32x16_bf16.
//   Same verified R2 schedule (4 phases, one-phase-ahead register prefetch,
//   2 barriers/phase, counted vmcnt), but 32x32 MFMA shape:
//     - LDS traffic identical (24 x b128 per wave per K-tile)
//     - MFMA pipe time -17% (measured 32x32 ceiling 2382 vs 2075 TF)
//     - MFMA instruction count halved (32/wave/tile)
//   Wave tile 128x64: 4 m-frags (32 rows) x 2 n-frags (32 cols);
//   K-frag = 16, grouped in kf-pairs: kfA = {0,1}, kfB = {2,3}.
//   Phases: P1 (lo m-frags 0-1, kfA) P2 (lo, kfB) P3 (hi 2-3, kfA) P4 (hi, kfB)
//   Sets S0 = {sa0[2][2], sb0[2][2]} (kfA), S1 (kfB); windows prefetch one
//   phase ahead; w4 prefetches next tile's S0 from nbuf.
//   Staging regions (wave-aware): Alo = row-bases {0,128}, Ahi = {64,192}.
//     w1: stage Ahi(t+1)->nbuf (2); vmcnt(8) retires Ahi(t)  [tail: 0]
//     w3: stage Alo(t+2)->buf  (2); vmcnt(4) retires Alo(t+1)+B(t+1) [tail: 0]
//     w4: stage B(t+2)->buf (4)
//   Steady ledger at w1-end: [Ahi(t)2 | Alo(t+1)2 B(t+1)4 Ahi(t+1)2] -> 8 ✓
//   at w3-end: [Alo(t+1)2 B(t+1)4 | Ahi(t+1)2 Alo(t+2)2] -> 4 ✓
// ---------------------------------------------------------------------------
__global__ __launch_bounds__(512, 2)
void gemm_lse_kernel(const unsigned short* __restrict__ A,
                     const unsigned short* __restrict__ Bt,
                     const float* __restrict__ norm2,
                     float* __restrict__ sums) {
    __shared__ __attribute__((aligned(16))) unsigned short As[2][BM][BK]; // 64 KB
    __shared__ __attribute__((aligned(16))) unsigned short Bs[2][BN][BK]; // 64 KB

    const int tid  = threadIdx.x;
    const int wave = tid >> 6;
    const int lane = tid & 63;
    const int l31  = lane & 31;
    const int l7   = lane & 7;
    const int hi32 = lane >> 5;    // 0..1
    const int wm   = wave >> 2;    // 0..1  (m half: 128 rows)
    const int wn   = wave & 3;     // 0..3  (n quarter: 64 cols)

    // ---- block -> (m0,h0): XCD-chunked, 16x16 supertile per XCD ----
    const int bid = blockIdx.x;
    const int xcd = bid & 7;
    const int li  = bid >> 3;                       // 0..255
    const int m0  = ((xcd & 1) * 16 + (li & 15)) * BM;   // mb 0..31
    const int h0  = ((xcd >> 1) * 16 + (li >> 4)) * BN;  // hb 0..63

    // staging: linear LDS dest (base + lane*16), pre-swizzled global source.
    const int ri = lane >> 3;
    const int sc = (l7 ^ ri) * 8;
    const unsigned short* ag = A  + (size_t)(m0 + wave * 8 + ri) * K_DIM + sc;
    const unsigned short* bg = Bt + (size_t)(h0 + wave * 8 + ri) * K_DIM + sc;

#define STAGE_A(BF_, BASE_, KT_)                                               \
    __builtin_amdgcn_global_load_lds(                                          \
        (const __attribute__((address_space(1))) void*)                        \
            (ag + (size_t)(BASE_) * K_DIM + (KT_) * BK),                       \
        (__attribute__((address_space(3))) void*)&As[BF_][(BASE_) + wave * 8][0], \
        16, 0, 0)
#define STAGE_B(BF_, BASE_, KT_)                                               \
    __builtin_amdgcn_global_load_lds(                                          \
        (const __attribute__((address_space(1))) void*)                        \
            (bg + (size_t)(BASE_) * K_DIM + (KT_) * BK),                       \
        (__attribute__((address_space(3))) void*)&Bs[BF_][(BASE_) + wave * 8][0], \
        16, 0, 0)

    // fragment reads (32x32x16): lane reads 16B at chunk = kf*2 + hi32 of its
    // row; XOR-8 swizzled slot = chunk ^ (row&7), row&7 == lane&7.
#define LDA32(D_, BF_, FM_, KF_)                                               \
    D_ = *(const short8*)&As[BF_][wm * 128 + (FM_) * 32 + l31]                 \
                             [(((KF_) * 2 + hi32) ^ l7) * 8]
#define LDB32(D_, BF_, FN_, KF_)                                               \
    D_ = *(const short8*)&Bs[BF_][wn * 64 + (FN_) * 32 + l31]                  \
                             [(((KF_) * 2 + hi32) ^ l7) * 8]

    f32x16 acc[4][2];
#pragma unroll
    for (int i = 0; i < 4; ++i)
#pragma unroll
        for (int j = 0; j < 2; ++j)
#pragma unroll
            for (int r = 0; r < 16; ++r)
                acc[i][j][r] = 0.f;

    short8 sa0[2][2], sb0[2][2], sa1[2][2], sb1[2][2];

    // 8 MFMA: kf-pair outer (4 independent then 4 chained per acc)
#define CLUSTER(FB_, SA_, SB_)                                                 \
    __builtin_amdgcn_s_barrier();                                              \
    __builtin_amdgcn_s_setprio(1);                                             \
    _Pragma("unroll")                                                          \
    for (int kk = 0; kk < 2; ++kk)                                             \
        _Pragma("unroll")                                                      \
        for (int fm = 0; fm < 2; ++fm)                                         \
            _Pragma("unroll")                                                  \
            for (int fn = 0; fn < 2; ++fn)                                     \
                acc[(FB_) + fm][fn] = __builtin_amdgcn_mfma_f32_32x32x16_bf16( \
                    SA_[fm][kk], SB_[fn][kk], acc[(FB_) + fm][fn], 0, 0, 0);   \
    __builtin_amdgcn_s_setprio(0);                                             \
    __builtin_amdgcn_s_barrier()

    // ---- prologue: A(0) full, B(0), Alo(1), B(1); retire tile-0 data ------
    STAGE_A(0, 0, 0);   STAGE_A(0, 128, 0);    // A0 lo
    STAGE_A(0, 64, 0);  STAGE_A(0, 192, 0);    // A0 hi
    STAGE_B(0, 0, 0);   STAGE_B(0, 64, 0);     // B0
    STAGE_B(0, 128, 0); STAGE_B(0, 192, 0);
    STAGE_A(1, 0, 1);   STAGE_A(1, 128, 1);    // A1 lo
    STAGE_B(1, 0, 1);   STAGE_B(1, 64, 1);     // B1
    STAGE_B(1, 128, 1); STAGE_B(1, 192, 1);
    asm volatile("s_waitcnt vmcnt(6)" ::: "memory");
    __builtin_amdgcn_s_barrier();

    // pre-loop prefetch: S0 <- {A(0) lo kfA, B(0) kfA}
    LDA32(sa0[0][0], 0, 0, 0); LDA32(sa0[0][1], 0, 0, 1);
    LDA32(sa0[1][0], 0, 1, 0); LDA32(sa0[1][1], 0, 1, 1);
    LDB32(sb0[0][0], 0, 0, 0); LDB32(sb0[0][1], 0, 0, 1);
    LDB32(sb0[1][0], 0, 1, 0); LDB32(sb0[1][1], 0, 1, 1);

#pragma unroll 2
    for (int t = 0; t < NKT; ++t) {
        const int buf  = t & 1;
        const int nbuf = buf ^ 1;

        // ---- w1: stage Ahi(t+1); read S1 <- {A lo kfB, B kfB} -------------
        if (t < NKT - 1) { STAGE_A(nbuf, 64, t + 1); STAGE_A(nbuf, 192, t + 1); }
        LDA32(sa1[0][0], buf, 0, 2); LDA32(sa1[0][1], buf, 0, 3);
        LDA32(sa1[1][0], buf, 1, 2); LDA32(sa1[1][1], buf, 1, 3);
        LDB32(sb1[0][0], buf, 0, 2); LDB32(sb1[0][1], buf, 0, 3);
        LDB32(sb1[1][0], buf, 1, 2); LDB32(sb1[1][1], buf, 1, 3);
        if (t < NKT - 1) { asm volatile("s_waitcnt vmcnt(8)" ::: "memory"); }
        else             { asm volatile("s_waitcnt vmcnt(0)" ::: "memory"); }
        CLUSTER(0, sa0, sb0);                    // P1: lo x kfA

        // ---- w2: read S0.a <- A hi kfA ------------------------------------
        LDA32(sa0[0][0], buf, 2, 0); LDA32(sa0[0][1], buf, 2, 1);
        LDA32(sa0[1][0], buf, 3, 0); LDA32(sa0[1][1], buf, 3, 1);
        CLUSTER(0, sa1, sb1);                    // P2: lo x kfB

        // ---- w3: stage Alo(t+2); read S1.a <- A hi kfB --------------------
        if (t < NKT - 2) { STAGE_A(buf, 0, t + 2); STAGE_A(buf, 128, t + 2); }
        LDA32(sa1[0][0], buf, 2, 2); LDA32(sa1[0][1], buf, 2, 3);
        LDA32(sa1[1][0], buf, 3, 2); LDA32(sa1[1][1], buf, 3, 3);
        if (t < NKT - 2) { asm volatile("s_waitcnt vmcnt(4)" ::: "memory"); }
        else             { asm volatile("s_waitcnt vmcnt(0)" ::: "memory"); }
        CLUSTER(2, sa0, sb0);                    // P3: hi x kfA

        // ---- w4: stage B(t+2); read S0 <- next tile {A lo kfA, B kfA} -----
        if (t < NKT - 2) {
            STAGE_B(buf, 0, t + 2);   STAGE_B(buf, 64, t + 2);
            STAGE_B(buf, 128, t + 2); STAGE_B(buf, 192, t + 2);
        }
        if (t < NKT - 1) {
            LDA32(sa0[0][0], nbuf, 0, 0); LDA32(sa0[0][1], nbuf, 0, 1);
            LDA32(sa0[1][0], nbuf, 1, 0); LDA32(sa0[1][1], nbuf, 1, 1);
            LDB32(sb0[0][0], nbuf, 0, 0); LDB32(sb0[0][1], nbuf, 0, 1);
            LDB32(sb0[1][0], nbuf, 1, 0); LDB32(sb0[1][1], nbuf, 1, 1);
        }
        CLUSTER(2, sa1, sb1);                    // P4: hi x kfB
    }

    // ---- epilogue. 32x32 C/D: col = lane&31, row = (r&3)+8*(r>>2)+4*hi32 --
    float rn2[2];
#pragma unroll
    for (int fn = 0; fn < 2; ++fn)
        rn2[fn] = rsqrtf(norm2[h0 + wn * 64 + fn * 32 + l31]);

#pragma unroll
    for (int i = 0; i < 4; ++i) {
#pragma unroll
        for (int r = 0; r < 16; ++r) {
            float s = __expf(acc[i][0][r] * rn2[0]) + __expf(acc[i][1][r] * rn2[1]);
            s += __shfl_xor(s, 1);
            s += __shfl_xor(s, 2);
            s += __shfl_xor(s, 4);
            s += __shfl_xor(s, 8);
            s += __shfl_xor(s, 16);
            if (l31 == 0)
                atomicAdd(&sums[m0 + wm * 128 + i * 32 +
                                (r & 3) + 8 * (r >> 2) + 4 * hi32], s);
        }
    }
#undef STAGE_A
#undef STAGE_B
#undef LDA32
#undef LDB32
#undef CLUSTER
}

// ---------------------------------------------------------------------------
// Kernel 4: out[m] = log(sums[m])   (BETA = 1)
// ---------------------------------------------------------------------------
__global__ void finalize_kernel(const float* __restrict__ sums,
                                float* __restrict__ out, int n) {
    int i = blockIdx.x * blockDim.x + threadIdx.x;
    if (i < n) out[i] = logf(sums[i]);
}

// ---------------------------------------------------------------------------
extern "C" void kernel_launch(void* const* d_in, const int* in_sizes, int n_in,
                              void* d_out, int out_size, void* d_ws, size_t ws_size,
                              hipStream_t stream) {
    const float* g = (const float*)d_in[0];   // [4,2048,4096] fp32
    const float* W = (const float*)d_in[1];   // [4096,16384] fp32
    float* out = (float*)d_out;               // [8192] fp32

    char* ws = (char*)d_ws;
    unsigned short* gbf   = (unsigned short*)ws;                              // 64 MB
    unsigned short* wt    = (unsigned short*)(ws + (size_t)67108864);         // 128 MB
    float*          norm2 = (float*)(ws + (size_t)67108864 + 134217728);      // 64 KB
    float*          sums  = (float*)(ws + (size_t)67108864 + 134217728 + 65536); // 32 KB

    hipMemsetAsync(norm2, 0, (H_DIM + M_TOTAL) * sizeof(float), stream);

    cast_bf16_kernel<<<(M_TOTAL * (long)K_DIM) / (256 * 8), 256, 0, stream>>>(
        g, gbf, (long)M_TOTAL * K_DIM);

    transpose_norm_kernel<<<dim3(H_DIM / 64, K_DIM / 64), 256, 0, stream>>>(
        W, wt, norm2);

    gemm_lse_kernel<<<(H_DIM / BN) * (M_TOTAL / BM), 512, 0, stream>>>(
        gbf, wt, norm2, sums);

    finalize_kernel<<<(M_TOTAL + 255) / 256, 256, 0, stream>>>(sums, out, M_TOTAL);
}